// Round 7
// baseline (578.893 us; speedup 1.0000x reference)
//
#include <hip/hip_runtime.h>
#include <hip/hip_bf16.h>
#include <stdint.h>

typedef uint32_t u32;
typedef uint64_t u64;
typedef float f4 __attribute__((ext_vector_type(4)));

// Problem constants (from reference)
constexpr int BATCH = 8;
constexpr int L = 32768;
constexpr int C = 128;            // channels
constexpr int N = BATCH * L;      // 262144 points
constexpr int NBUCKET = 1 << 14;  // buckets on top-14 bits of 30-bit key
constexpr u32 DUP_CAP = 65536;
// key = (batch<<27)|(x<<18)|(y<<9)|z (30 bits); bucket = key >> 16.
// Global unique-rank r = hoff[bucket] + localRank(distinct key within bucket).
// inv_partial[p] = bucket<<18 | dup<<17 | first<<16 | localRank(16b).

// ctrl layout (u32 words)
constexpr int OFF_HIST   = 0;      // 16384
constexpr int OFF_DUPCNT = 16384;  // 1
constexpr int OFF_DONEA  = 16385;  // 1
constexpr int OFF_DONED  = 16386;  // 1 (+1 pad)
constexpr int OFF_BSTART = 16388;  // 16385
constexpr int OFF_HCNT   = 32773;  // 16384
constexpr int OFF_HOFF   = 49157;  // 16385 (hoff[NBUCKET] = nUnique)

// Exclusive scan of 16384 u32 with 256 threads. Agent-scope atomic loads so a
// last-block caller sees other blocks' values despite per-XCD L2s.
__device__ void scan16k_256(const u32* __restrict__ cnt, u32* __restrict__ outp) {
    __shared__ u32 ssum[256];
    int t = threadIdx.x;
    u32 sum = 0;
    for (int k = 0; k < 64; ++k)
        sum += __hip_atomic_load(&cnt[t * 64 + k], __ATOMIC_RELAXED,
                                 __HIP_MEMORY_SCOPE_AGENT);
    ssum[t] = sum;
    __syncthreads();
    for (int off = 1; off < 256; off <<= 1) {
        u32 v = (t >= off) ? ssum[t - off] : 0u;
        __syncthreads();
        ssum[t] += v;
        __syncthreads();
    }
    u32 run = (t == 0) ? 0u : ssum[t - 1];
    for (int k = 0; k < 64; ++k) {
        u32 c = __hip_atomic_load(&cnt[t * 64 + k], __ATOMIC_RELAXED,
                                  __HIP_MEMORY_SCOPE_AGENT);
        outp[t * 64 + k] = run;
        run += c;
    }
    if (t == 255) outp[NBUCKET] = run;
}

// ---- A: keys + hist (atomic slot) + keyslot; last block scans hist->bstart ----
__global__ __launch_bounds__(256) void kA(const int* __restrict__ coords,
                                          u64* __restrict__ keyslot,
                                          u32* __restrict__ ctrl) {
    int i = blockIdx.x * 256 + threadIdx.x;
    u32* hist = ctrl + OFF_HIST;
    int batch = i >> 15;  // i / L
    int x = coords[3 * i + 0];
    int y = coords[3 * i + 1];
    int z = coords[3 * i + 2];
    u32 key = ((u32)batch << 27) | ((u32)x << 18) | ((u32)y << 9) | (u32)z;
    u32 slot = atomicAdd(&hist[key >> 16], 1u);  // within-bucket slot (order-free)
    keyslot[i] = ((u64)key << 32) | slot;

    __shared__ int isLast;
    __threadfence();
    __syncthreads();
    if (threadIdx.x == 0) {
        u32 old = atomicAdd(&ctrl[OFF_DONEA], 1u);
        isLast = (old == gridDim.x - 1);
    }
    __syncthreads();
    if (isLast) {
        __threadfence();
        scan16k_256(hist, ctrl + OFF_BSTART);
    }
}

// ---- C: place (key,idx) at bstart[b]+slot (atomic-free) ----
__global__ __launch_bounds__(256) void kC(const u64* __restrict__ keyslot,
                                          const u32* __restrict__ ctrl,
                                          u64* __restrict__ bucketed) {
    const u32* bstart = ctrl + OFF_BSTART;
    int i = blockIdx.x * 256 + threadIdx.x;
    u64 ks = keyslot[i];
    u32 key = (u32)(ks >> 32);
    u32 slot = (u32)ks;
    u32 pos = bstart[key >> 16] + slot;
    bucketed[pos] = ((u64)key << 32) | (u32)i;
}

// ---- D: wave-per-bucket in-register dedup -> inv_partial, dupList, hcnt;
//         last block scans hcnt -> hoff ----
__global__ __launch_bounds__(256) void kD(const u64* __restrict__ bucketed,
                                          u32* __restrict__ inv_partial,
                                          u64* __restrict__ dupList,
                                          u32* __restrict__ ctrl) {
    const u32* bstart = ctrl + OFF_BSTART;
    u32* hcnt = ctrl + OFF_HCNT;
    u32* dupCount = ctrl + OFF_DUPCNT;
    int wid = (blockIdx.x * 256 + threadIdx.x) >> 6;  // == bucket id (exact cover)
    int lane = threadIdx.x & 63;
    int b = wid;
    u32 s0 = bstart[b];
    u32 m = bstart[b + 1] - s0;
    if (m == 0) {
        if (lane == 0)
            __hip_atomic_store(&hcnt[b], 0u, __ATOMIC_RELAXED, __HIP_MEMORY_SCOPE_AGENT);
    } else if (m <= 64) {
        // one element per lane, all-pairs via shfl
        u64 v = (lane < (int)m) ? bucketed[s0 + lane] : ~0ull;
        u32 key = (u32)(v >> 32), p = (u32)v;
        bool valid = lane < (int)m;
        bool first = valid;
        bool dup = false;
        for (u32 k = 0; k < m; ++k) {
            u32 kk = (u32)__shfl((int)key, (int)k);
            u32 pk = (u32)__shfl((int)p, (int)k);
            if (valid && (int)k != lane && kk == key) {
                dup = true;
                if (pk < p) first = false;  // head = min original idx among equals
            }
        }
        u64 hm = __ballot(valid && first);
        u32 lr = 0;
        for (u32 k = 0; k < m; ++k) {
            u32 kk = (u32)__shfl((int)key, (int)k);
            if (valid && ((hm >> k) & 1ull) && kk < key) lr++;
        }
        if (valid) {
            inv_partial[p] = ((u32)b << 18) | (dup ? (1u << 17) : 0) |
                             (first ? (1u << 16) : 0) | (lr & 0xFFFF);
            if (dup && first) {
                u32 slot = atomicAdd(dupCount, 1u);
                if (slot < DUP_CAP) dupList[slot] = ((u64)key << 32) | lr;
            }
        }
        if (lane == 0)
            __hip_atomic_store(&hcnt[b], (u32)__popcll(hm), __ATOMIC_RELAXED,
                               __HIP_MEMORY_SCOPE_AGENT);
    } else {
        // slow path: per-element O(m^2) (never taken for this input)
        int dc = 0;
        for (u32 j = lane; j < m; j += 64) {
            u64 vj = bucketed[s0 + j];
            u32 kj = (u32)(vj >> 32), pj = (u32)vj;
            bool first = true, dup = false;
            u32 lr = 0;
            for (u32 k = 0; k < m; ++k) {
                if (k == j) continue;
                u64 vk = bucketed[s0 + k];
                u32 kk = (u32)(vk >> 32), pk = (u32)vk;
                if (kk == kj) {
                    dup = true;
                    if (pk < pj) first = false;
                } else if (kk < kj) {
                    bool f2 = true;  // count key kk once: only at its head element
                    for (u32 k2 = 0; k2 < m; ++k2) {
                        if (k2 == k) continue;
                        u64 v2 = bucketed[s0 + k2];
                        if ((u32)(v2 >> 32) == kk && (u32)v2 < pk) { f2 = false; break; }
                    }
                    if (f2) lr++;
                }
            }
            inv_partial[pj] = ((u32)b << 18) | (dup ? (1u << 17) : 0) |
                              (first ? (1u << 16) : 0) | (lr & 0xFFFF);
            if (dup && first) {
                u32 slot = atomicAdd(dupCount, 1u);
                if (slot < DUP_CAP) dupList[slot] = ((u64)kj << 32) | (lr & 0xFFFF);
            }
            dc += first ? 1 : 0;
        }
        for (int off = 32; off > 0; off >>= 1) dc += __shfl_down(dc, off);
        if (lane == 0)
            __hip_atomic_store(&hcnt[b], (u32)dc, __ATOMIC_RELAXED,
                               __HIP_MEMORY_SCOPE_AGENT);
    }

    __shared__ int isLast;
    __threadfence();
    __syncthreads();
    if (threadIdx.x == 0) {
        u32 old = atomicAdd(&ctrl[OFF_DONED], 1u);
        isLast = (old == gridDim.x - 1);
    }
    __syncthreads();
    if (isLast) {
        __threadfence();
        scan16k_256(hcnt, ctrl + OFF_HOFF);
    }
}

// ---- G: streaming scatter (4x independent rows) + dup fixup + tail zero ----
constexpr int G_BLOCKS = 8192;  // 65536 slots x 4 rows = N

__global__ __launch_bounds__(256) void kG(const u32* __restrict__ inv_partial,
                                          const float* __restrict__ feats,
                                          const u64* __restrict__ bucketed,
                                          const u64* __restrict__ dupList,
                                          const u32* __restrict__ ctrl,
                                          float* __restrict__ out) {
    const u32* bstart = ctrl + OFF_BSTART;
    const u32* hoff = ctrl + OFF_HOFF;
    const f4* F = (const f4*)feats;
    f4* O = (f4*)out;
    int gid = blockIdx.x * 256 + threadIdx.x;
    int slot = gid >> 5;   // row group
    int q = gid & 31;      // float4 slot within the 128-ch row

    // main scatter: 4 independent rows per thread (sequential reads, nt random writes)
    {
        int p0 = slot, p1 = slot + 65536, p2 = slot + 131072, p3 = slot + 196608;
        u32 i0 = inv_partial[p0], i1 = inv_partial[p1];
        u32 i2 = inv_partial[p2], i3 = inv_partial[p3];
        f4 v0 = F[(size_t)p0 * 32 + q];
        f4 v1 = F[(size_t)p1 * 32 + q];
        f4 v2 = F[(size_t)p2 * 32 + q];
        f4 v3 = F[(size_t)p3 * 32 + q];
        if (!(i0 & (1u << 17))) {
            u32 r = hoff[i0 >> 18] + (i0 & 0xFFFF);
            __builtin_nontemporal_store(v0, O + (size_t)r * 32 + q);
        }
        if (!(i1 & (1u << 17))) {
            u32 r = hoff[i1 >> 18] + (i1 & 0xFFFF);
            __builtin_nontemporal_store(v1, O + (size_t)r * 32 + q);
        }
        if (!(i2 & (1u << 17))) {
            u32 r = hoff[i2 >> 18] + (i2 & 0xFFFF);
            __builtin_nontemporal_store(v2, O + (size_t)r * 32 + q);
        }
        if (!(i3 & (1u << 17))) {
            u32 r = hoff[i3 >> 18] + (i3 & 0xFFFF);
            __builtin_nontemporal_store(v3, O + (size_t)r * 32 + q);
        }
    }

    // dup-segment fixup: one wave per segment, sum in ascending original index
    {
        int wv = gid >> 6;
        const int NW = G_BLOCKS * 4;
        int lane = threadIdx.x & 63;
        u32 nd = ctrl[OFF_DUPCNT];
        if (nd > DUP_CAP) nd = DUP_CAP;
        for (u32 d = (u32)wv; d < nd; d += (u32)NW) {
            u64 e = dupList[d];
            u32 key = (u32)(e >> 32);
            u32 lr = (u32)e;
            u32 r = hoff[key >> 16] + lr;
            u32 b = key >> 16;
            u32 s0 = bstart[b];
            u32 m = bstart[b + 1] - s0;
            if (lane < 32) {
                f4 acc = {0.f, 0.f, 0.f, 0.f};
                u32 prevP = 0;
                bool firstIter = true;
                for (;;) {  // next-smallest original index among equal keys
                    u32 best = 0xFFFFFFFFu;
                    for (u32 k = 0; k < m; ++k) {
                        u64 vk = bucketed[s0 + k];
                        if ((u32)(vk >> 32) == key) {
                            u32 pk = (u32)vk;
                            if ((firstIter || pk > prevP) && pk < best) best = pk;
                        }
                    }
                    if (best == 0xFFFFFFFFu) break;
                    acc += F[(size_t)best * 32 + lane];
                    prevP = best;
                    firstIter = false;
                }
                O[(size_t)r * 32 + lane] = acc;
            }
        }
    }

    // tail zero: rows [nUnique, N)
    {
        u32 nU = hoff[NBUCKET];
        u32 tailQuads = ((u32)N - nU) * 32u;
        const u32 tot = G_BLOCKS * 256;
        f4 z = {0.f, 0.f, 0.f, 0.f};
        for (u32 t = (u32)gid; t < tailQuads; t += tot) {
            u32 row = nU + (t >> 5);
            O[(size_t)row * 32 + (t & 31)] = z;
        }
    }
}

extern "C" void kernel_launch(void* const* d_in, const int* in_sizes, int n_in,
                              void* d_out, int out_size, void* d_ws, size_t ws_size,
                              hipStream_t stream) {
    const int* coords = (const int*)d_in[0];
    const float* feats = (const float*)d_in[1];
    float* out = (float*)d_out;

    char* w = (char*)d_ws;
    u64* bucketed   = (u64*)(w);                              // 2 MiB
    u64* keyslot    = (u64*)(w + (size_t)2 * 1024 * 1024);    // 2 MiB
    u32* inv_partial= (u32*)(w + (size_t)4 * 1024 * 1024);    // 1 MiB
    u64* dupList    = (u64*)(w + (size_t)5 * 1024 * 1024);    // 512 KiB
    u32* ctrl       = (u32*)(w + (size_t)5 * 1024 * 1024 + 512 * 1024);  // ~257 KiB

    // zero hist + dupCount + doneA + doneD (+pad): 16388 words
    hipMemsetAsync(ctrl, 0, (size_t)16388 * sizeof(u32), stream);

    kA<<<N / 256, 256, 0, stream>>>(coords, keyslot, ctrl);
    kC<<<N / 256, 256, 0, stream>>>(keyslot, ctrl, bucketed);
    kD<<<NBUCKET / 4, 256, 0, stream>>>(bucketed, inv_partial, dupList, ctrl);
    kG<<<G_BLOCKS, 256, 0, stream>>>(inv_partial, feats, bucketed, dupList, ctrl, out);
}

// Round 8
// 108.452 us; speedup vs baseline: 5.3378x; 5.3378x over previous
//
#include <hip/hip_runtime.h>
#include <hip/hip_bf16.h>
#include <stdint.h>

typedef uint32_t u32;
typedef uint64_t u64;
typedef float f4 __attribute__((ext_vector_type(4)));

// Problem constants (from reference)
constexpr int BATCH = 8;
constexpr int L = 32768;
constexpr int C = 128;            // channels
constexpr int N = BATCH * L;      // 262144 points
constexpr int NBUCKET = 1 << 14;  // buckets on top-14 bits of 30-bit key
constexpr u32 DUP_CAP = 65536;
// key = (batch<<27)|(x<<18)|(y<<9)|z (30 bits); bucket = key >> 16.
// Global unique-rank r = hoff[bucket] + localRank(distinct key within bucket).
// inv_partial[p] = bucket<<18 | dup<<17 | first<<16 | localRank(16b).

// ctrl layout (u32 words)
constexpr int OFF_HIST   = 0;      // 16384
constexpr int OFF_DUPCNT = 16384;  // 1 (+3 pad)
constexpr int OFF_BSTART = 16388;  // 16385
constexpr int OFF_HCNT   = 32773;  // 16384
constexpr int OFF_HOFF   = 49157;  // 16385 (hoff[NBUCKET] = nUnique)

// ---- A: keys + hist (atomic slot) + keyslot ----
__global__ __launch_bounds__(256) void kA(const int* __restrict__ coords,
                                          u64* __restrict__ keyslot,
                                          u32* __restrict__ ctrl) {
    int i = blockIdx.x * 256 + threadIdx.x;
    u32* hist = ctrl + OFF_HIST;
    int batch = i >> 15;  // i / L
    int x = coords[3 * i + 0];
    int y = coords[3 * i + 1];
    int z = coords[3 * i + 2];
    u32 key = ((u32)batch << 27) | ((u32)x << 18) | ((u32)y << 9) | (u32)z;
    u32 slot = atomicAdd(&hist[key >> 16], 1u);  // within-bucket slot (order-free)
    keyslot[i] = ((u64)key << 32) | slot;
}

// ---- scan: exclusive scan of 16384 u32 (1 block, 1024 thr — proven) ----
__global__ __launch_bounds__(1024) void k_scan(const u32* __restrict__ cnt,
                                               u32* __restrict__ outp) {
    __shared__ u32 s[1024];
    int t = threadIdx.x;
    u32 loc[16];
    u32 sum = 0;
    for (int k = 0; k < 16; ++k) { loc[k] = sum; sum += cnt[t * 16 + k]; }
    s[t] = sum;
    __syncthreads();
    for (int off = 1; off < 1024; off <<= 1) {
        u32 v = (t >= off) ? s[t - off] : 0u;
        __syncthreads();
        s[t] += v;
        __syncthreads();
    }
    u32 base = (t == 0) ? 0u : s[t - 1];
    for (int k = 0; k < 16; ++k) outp[t * 16 + k] = base + loc[k];
    if (t == 1023) outp[NBUCKET] = s[1023];
}

// ---- C: place (key,idx) at bstart[b]+slot (atomic-free) ----
__global__ __launch_bounds__(256) void kC(const u64* __restrict__ keyslot,
                                          const u32* __restrict__ ctrl,
                                          u64* __restrict__ bucketed) {
    const u32* bstart = ctrl + OFF_BSTART;
    int i = blockIdx.x * 256 + threadIdx.x;
    u64 ks = keyslot[i];
    u32 key = (u32)(ks >> 32);
    u32 slot = (u32)ks;
    u32 pos = bstart[key >> 16] + slot;
    bucketed[pos] = ((u64)key << 32) | (u32)i;
}

// ---- D: wave-per-bucket in-register dedup -> inv_partial, dupList, hcnt ----
__global__ __launch_bounds__(256) void kD(const u64* __restrict__ bucketed,
                                          u32* __restrict__ inv_partial,
                                          u64* __restrict__ dupList,
                                          u32* __restrict__ ctrl) {
    const u32* bstart = ctrl + OFF_BSTART;
    u32* hcnt = ctrl + OFF_HCNT;
    u32* dupCount = ctrl + OFF_DUPCNT;
    int b = (blockIdx.x * 256 + threadIdx.x) >> 6;  // bucket id (exact cover)
    int lane = threadIdx.x & 63;
    u32 s0 = bstart[b];
    u32 m = bstart[b + 1] - s0;
    if (m == 0) {
        if (lane == 0) hcnt[b] = 0;
    } else if (m <= 64) {
        // one element per lane, all-pairs via shfl
        u64 v = (lane < (int)m) ? bucketed[s0 + lane] : ~0ull;
        u32 key = (u32)(v >> 32), p = (u32)v;
        bool valid = lane < (int)m;
        bool first = valid;
        bool dup = false;
        for (u32 k = 0; k < m; ++k) {
            u32 kk = (u32)__shfl((int)key, (int)k);
            u32 pk = (u32)__shfl((int)p, (int)k);
            if (valid && (int)k != lane && kk == key) {
                dup = true;
                if (pk < p) first = false;  // head = min original idx among equals
            }
        }
        u64 hm = __ballot(valid && first);
        u32 lr = 0;
        for (u32 k = 0; k < m; ++k) {
            u32 kk = (u32)__shfl((int)key, (int)k);
            if (valid && ((hm >> k) & 1ull) && kk < key) lr++;
        }
        if (valid) {
            inv_partial[p] = ((u32)b << 18) | (dup ? (1u << 17) : 0) |
                             (first ? (1u << 16) : 0) | (lr & 0xFFFF);
            if (dup && first) {
                u32 slot = atomicAdd(dupCount, 1u);
                if (slot < DUP_CAP) dupList[slot] = ((u64)key << 32) | lr;
            }
        }
        if (lane == 0) hcnt[b] = (u32)__popcll(hm);
    } else {
        // slow path: per-element O(m^2) (never taken for this input)
        int dc = 0;
        for (u32 j = lane; j < m; j += 64) {
            u64 vj = bucketed[s0 + j];
            u32 kj = (u32)(vj >> 32), pj = (u32)vj;
            bool first = true, dup = false;
            u32 lr = 0;
            for (u32 k = 0; k < m; ++k) {
                if (k == j) continue;
                u64 vk = bucketed[s0 + k];
                u32 kk = (u32)(vk >> 32), pk = (u32)vk;
                if (kk == kj) {
                    dup = true;
                    if (pk < pj) first = false;
                } else if (kk < kj) {
                    bool f2 = true;  // count key kk once: only at its head element
                    for (u32 k2 = 0; k2 < m; ++k2) {
                        if (k2 == k) continue;
                        u64 v2 = bucketed[s0 + k2];
                        if ((u32)(v2 >> 32) == kk && (u32)v2 < pk) { f2 = false; break; }
                    }
                    if (f2) lr++;
                }
            }
            inv_partial[pj] = ((u32)b << 18) | (dup ? (1u << 17) : 0) |
                              (first ? (1u << 16) : 0) | (lr & 0xFFFF);
            if (dup && first) {
                u32 slot = atomicAdd(dupCount, 1u);
                if (slot < DUP_CAP) dupList[slot] = ((u64)kj << 32) | (lr & 0xFFFF);
            }
            dc += first ? 1 : 0;
        }
        for (int off = 32; off > 0; off >>= 1) dc += __shfl_down(dc, off);
        if (lane == 0) hcnt[b] = (u32)dc;
    }
}

// ---- G: streaming scatter (4x independent rows) + dup fixup + tail zero ----
constexpr int G_BLOCKS = 8192;  // 65536 slots x 4 rows = N

__global__ __launch_bounds__(256) void kG(const u32* __restrict__ inv_partial,
                                          const float* __restrict__ feats,
                                          const u64* __restrict__ bucketed,
                                          const u64* __restrict__ dupList,
                                          const u32* __restrict__ ctrl,
                                          float* __restrict__ out) {
    const u32* bstart = ctrl + OFF_BSTART;
    const u32* hoff = ctrl + OFF_HOFF;
    const f4* F = (const f4*)feats;
    f4* O = (f4*)out;
    int gid = blockIdx.x * 256 + threadIdx.x;
    int slot = gid >> 5;   // row group
    int q = gid & 31;      // float4 slot within the 128-ch row

    // main scatter: 4 independent rows per thread (sequential reads, nt random writes)
    {
        int p0 = slot, p1 = slot + 65536, p2 = slot + 131072, p3 = slot + 196608;
        u32 i0 = inv_partial[p0], i1 = inv_partial[p1];
        u32 i2 = inv_partial[p2], i3 = inv_partial[p3];
        f4 v0 = F[(size_t)p0 * 32 + q];
        f4 v1 = F[(size_t)p1 * 32 + q];
        f4 v2 = F[(size_t)p2 * 32 + q];
        f4 v3 = F[(size_t)p3 * 32 + q];
        if (!(i0 & (1u << 17))) {
            u32 r = hoff[i0 >> 18] + (i0 & 0xFFFF);
            __builtin_nontemporal_store(v0, O + (size_t)r * 32 + q);
        }
        if (!(i1 & (1u << 17))) {
            u32 r = hoff[i1 >> 18] + (i1 & 0xFFFF);
            __builtin_nontemporal_store(v1, O + (size_t)r * 32 + q);
        }
        if (!(i2 & (1u << 17))) {
            u32 r = hoff[i2 >> 18] + (i2 & 0xFFFF);
            __builtin_nontemporal_store(v2, O + (size_t)r * 32 + q);
        }
        if (!(i3 & (1u << 17))) {
            u32 r = hoff[i3 >> 18] + (i3 & 0xFFFF);
            __builtin_nontemporal_store(v3, O + (size_t)r * 32 + q);
        }
    }

    // dup-segment fixup: one wave per segment, sum in ascending original index
    {
        int wv = gid >> 6;
        const int NW = G_BLOCKS * 4;
        int lane = threadIdx.x & 63;
        u32 nd = ctrl[OFF_DUPCNT];
        if (nd > DUP_CAP) nd = DUP_CAP;
        for (u32 d = (u32)wv; d < nd; d += (u32)NW) {
            u64 e = dupList[d];
            u32 key = (u32)(e >> 32);
            u32 lr = (u32)e;
            u32 b = key >> 16;
            u32 r = hoff[b] + lr;
            u32 s0 = bstart[b];
            u32 m = bstart[b + 1] - s0;
            if (lane < 32) {
                f4 acc = {0.f, 0.f, 0.f, 0.f};
                u32 prevP = 0;
                bool firstIter = true;
                for (;;) {  // next-smallest original index among equal keys
                    u32 best = 0xFFFFFFFFu;
                    for (u32 k = 0; k < m; ++k) {
                        u64 vk = bucketed[s0 + k];
                        if ((u32)(vk >> 32) == key) {
                            u32 pk = (u32)vk;
                            if ((firstIter || pk > prevP) && pk < best) best = pk;
                        }
                    }
                    if (best == 0xFFFFFFFFu) break;
                    acc += F[(size_t)best * 32 + lane];
                    prevP = best;
                    firstIter = false;
                }
                O[(size_t)r * 32 + lane] = acc;
            }
        }
    }

    // tail zero: rows [nUnique, N)
    {
        u32 nU = hoff[NBUCKET];
        u32 tailQuads = ((u32)N - nU) * 32u;
        const u32 tot = G_BLOCKS * 256;
        f4 z = {0.f, 0.f, 0.f, 0.f};
        for (u32 t = (u32)gid; t < tailQuads; t += tot) {
            u32 row = nU + (t >> 5);
            O[(size_t)row * 32 + (t & 31)] = z;
        }
    }
}

extern "C" void kernel_launch(void* const* d_in, const int* in_sizes, int n_in,
                              void* d_out, int out_size, void* d_ws, size_t ws_size,
                              hipStream_t stream) {
    const int* coords = (const int*)d_in[0];
    const float* feats = (const float*)d_in[1];
    float* out = (float*)d_out;

    char* w = (char*)d_ws;
    u64* bucketed    = (u64*)(w);                              // 2 MiB
    u64* keyslot     = (u64*)(w + (size_t)2 * 1024 * 1024);    // 2 MiB
    u32* inv_partial = (u32*)(w + (size_t)4 * 1024 * 1024);    // 1 MiB
    u64* dupList     = (u64*)(w + (size_t)5 * 1024 * 1024);    // 512 KiB
    u32* ctrl        = (u32*)(w + (size_t)5 * 1024 * 1024 + 512 * 1024);  // ~257 KiB

    // zero hist + dupCount (contiguous 16385 words)
    hipMemsetAsync(ctrl, 0, (size_t)16385 * sizeof(u32), stream);

    kA<<<N / 256, 256, 0, stream>>>(coords, keyslot, ctrl);
    k_scan<<<1, 1024, 0, stream>>>(ctrl + OFF_HIST, ctrl + OFF_BSTART);
    kC<<<N / 256, 256, 0, stream>>>(keyslot, ctrl, bucketed);
    kD<<<NBUCKET / 4, 256, 0, stream>>>(bucketed, inv_partial, dupList, ctrl);
    k_scan<<<1, 1024, 0, stream>>>(ctrl + OFF_HCNT, ctrl + OFF_HOFF);
    kG<<<G_BLOCKS, 256, 0, stream>>>(inv_partial, feats, bucketed, dupList, ctrl, out);
}

// Round 9
// 105.068 us; speedup vs baseline: 5.5097x; 1.0322x over previous
//
#include <hip/hip_runtime.h>
#include <hip/hip_bf16.h>
#include <stdint.h>

typedef uint32_t u32;
typedef uint64_t u64;
typedef float f4 __attribute__((ext_vector_type(4)));

// Problem constants (from reference)
constexpr int BATCH = 8;
constexpr int L = 32768;
constexpr int C = 128;            // channels
constexpr int N = BATCH * L;      // 262144 points
constexpr int NBUCKET = 1 << 14;  // buckets on top-14 bits of 30-bit key
constexpr u32 DUP_CAP = 65536;
// key = (batch<<27)|(x<<18)|(y<<9)|z (30 bits); bucket = key >> 16.
// Global unique-rank r = hoff[bucket] + localRank(distinct key within bucket).
// inv_partial[p] = bucket<<18 | dup<<17 | first<<16 | localRank(16b).

// ctrl layout (u32 words)
constexpr int OFF_HIST   = 0;      // 16384
constexpr int OFF_DUPCNT = 16384;  // 1 (+3 pad)
constexpr int OFF_BSTART = 16388;  // 16385
constexpr int OFF_HCNT   = 32773;  // 16384
constexpr int OFF_HOFF   = 49157;  // 16385 (hoff[NBUCKET] = nUnique)

// ---- A: keys + hist (atomic slot) + keyslot ----
__global__ __launch_bounds__(256) void kA(const int* __restrict__ coords,
                                          u64* __restrict__ keyslot,
                                          u32* __restrict__ ctrl) {
    int i = blockIdx.x * 256 + threadIdx.x;
    u32* hist = ctrl + OFF_HIST;
    int batch = i >> 15;  // i / L
    int x = coords[3 * i + 0];
    int y = coords[3 * i + 1];
    int z = coords[3 * i + 2];
    u32 key = ((u32)batch << 27) | ((u32)x << 18) | ((u32)y << 9) | (u32)z;
    u32 slot = atomicAdd(&hist[key >> 16], 1u);  // within-bucket slot (order-free)
    keyslot[i] = ((u64)key << 32) | slot;
}

// ---- scan: exclusive scan of 16384 u32 (1 block, 1024 thr — proven) ----
__global__ __launch_bounds__(1024) void k_scan(const u32* __restrict__ cnt,
                                               u32* __restrict__ outp) {
    __shared__ u32 s[1024];
    int t = threadIdx.x;
    u32 loc[16];
    u32 sum = 0;
    for (int k = 0; k < 16; ++k) { loc[k] = sum; sum += cnt[t * 16 + k]; }
    s[t] = sum;
    __syncthreads();
    for (int off = 1; off < 1024; off <<= 1) {
        u32 v = (t >= off) ? s[t - off] : 0u;
        __syncthreads();
        s[t] += v;
        __syncthreads();
    }
    u32 base = (t == 0) ? 0u : s[t - 1];
    for (int k = 0; k < 16; ++k) outp[t * 16 + k] = base + loc[k];
    if (t == 1023) outp[NBUCKET] = s[1023];
}

// ---- C: place (key,idx) at bstart[b]+slot (atomic-free) ----
__global__ __launch_bounds__(256) void kC(const u64* __restrict__ keyslot,
                                          const u32* __restrict__ ctrl,
                                          u64* __restrict__ bucketed) {
    const u32* bstart = ctrl + OFF_BSTART;
    int i = blockIdx.x * 256 + threadIdx.x;
    u64 ks = keyslot[i];
    u32 key = (u32)(ks >> 32);
    u32 slot = (u32)ks;
    u32 pos = bstart[key >> 16] + slot;
    bucketed[pos] = ((u64)key << 32) | (u32)i;
}

// ---- D: wave-per-bucket in-register dedup -> inv_partial, dupList, hcnt ----
__global__ __launch_bounds__(256) void kD(const u64* __restrict__ bucketed,
                                          u32* __restrict__ inv_partial,
                                          u64* __restrict__ dupList,
                                          u32* __restrict__ ctrl) {
    const u32* bstart = ctrl + OFF_BSTART;
    u32* hcnt = ctrl + OFF_HCNT;
    u32* dupCount = ctrl + OFF_DUPCNT;
    int b = (blockIdx.x * 256 + threadIdx.x) >> 6;  // bucket id (exact cover)
    int lane = threadIdx.x & 63;
    u32 s0 = bstart[b];
    u32 m = bstart[b + 1] - s0;
    if (m == 0) {
        if (lane == 0) hcnt[b] = 0;
    } else if (m <= 64) {
        // one element per lane, all-pairs via shfl
        u64 v = (lane < (int)m) ? bucketed[s0 + lane] : ~0ull;
        u32 key = (u32)(v >> 32), p = (u32)v;
        bool valid = lane < (int)m;
        bool first = valid;
        bool dup = false;
        for (u32 k = 0; k < m; ++k) {
            u32 kk = (u32)__shfl((int)key, (int)k);
            u32 pk = (u32)__shfl((int)p, (int)k);
            if (valid && (int)k != lane && kk == key) {
                dup = true;
                if (pk < p) first = false;  // head = min original idx among equals
            }
        }
        u64 hm = __ballot(valid && first);
        u32 lr = 0;
        for (u32 k = 0; k < m; ++k) {
            u32 kk = (u32)__shfl((int)key, (int)k);
            if (valid && ((hm >> k) & 1ull) && kk < key) lr++;
        }
        if (valid) {
            inv_partial[p] = ((u32)b << 18) | (dup ? (1u << 17) : 0) |
                             (first ? (1u << 16) : 0) | (lr & 0xFFFF);
            if (dup && first) {
                u32 slot = atomicAdd(dupCount, 1u);
                if (slot < DUP_CAP) dupList[slot] = ((u64)key << 32) | lr;
            }
        }
        if (lane == 0) hcnt[b] = (u32)__popcll(hm);
    } else {
        // slow path: per-element O(m^2) (never taken for this input)
        int dc = 0;
        for (u32 j = lane; j < m; j += 64) {
            u64 vj = bucketed[s0 + j];
            u32 kj = (u32)(vj >> 32), pj = (u32)vj;
            bool first = true, dup = false;
            u32 lr = 0;
            for (u32 k = 0; k < m; ++k) {
                if (k == j) continue;
                u64 vk = bucketed[s0 + k];
                u32 kk = (u32)(vk >> 32), pk = (u32)vk;
                if (kk == kj) {
                    dup = true;
                    if (pk < pj) first = false;
                } else if (kk < kj) {
                    bool f2 = true;  // count key kk once: only at its head element
                    for (u32 k2 = 0; k2 < m; ++k2) {
                        if (k2 == k) continue;
                        u64 v2 = bucketed[s0 + k2];
                        if ((u32)(v2 >> 32) == kk && (u32)v2 < pk) { f2 = false; break; }
                    }
                    if (f2) lr++;
                }
            }
            inv_partial[pj] = ((u32)b << 18) | (dup ? (1u << 17) : 0) |
                              (first ? (1u << 16) : 0) | (lr & 0xFFFF);
            if (dup && first) {
                u32 slot = atomicAdd(dupCount, 1u);
                if (slot < DUP_CAP) dupList[slot] = ((u64)kj << 32) | (lr & 0xFFFF);
            }
            dc += first ? 1 : 0;
        }
        for (int off = 32; off > 0; off >>= 1) dc += __shfl_down(dc, off);
        if (lane == 0) hcnt[b] = (u32)dc;
    }
}

// ---- G: streaming scatter (1 row per 32-thread group — measured-best shape)
//         + dup fixup + tail zero ----
constexpr int ROWS_PER_BLOCK = 8;
constexpr int G_BLOCKS = N / ROWS_PER_BLOCK;  // 32768

__global__ __launch_bounds__(256) void kG(const u32* __restrict__ inv_partial,
                                          const float* __restrict__ feats,
                                          const u64* __restrict__ bucketed,
                                          const u64* __restrict__ dupList,
                                          const u32* __restrict__ ctrl,
                                          float* __restrict__ out) {
    const u32* bstart = ctrl + OFF_BSTART;
    const u32* hoff = ctrl + OFF_HOFF;
    const f4* F = (const f4*)feats;
    f4* O = (f4*)out;
    int gid = blockIdx.x * 256 + threadIdx.x;

    // main scatter: one thread = one float4 of one row (sequential read, nt random write)
    {
        int p = gid >> 5;   // input row
        int q = gid & 31;   // float4 slot within the 128-ch row
        u32 ip = inv_partial[p];
        f4 v = F[(size_t)p * 32 + q];
        if (!(ip & (1u << 17))) {
            u32 r = hoff[ip >> 18] + (ip & 0xFFFF);
            __builtin_nontemporal_store(v, O + (size_t)r * 32 + q);
        }
    }

    // dup-segment fixup: one wave per segment, sum in ascending original index
    {
        int wv = gid >> 6;
        const int NW = G_BLOCKS * 4;
        int lane = threadIdx.x & 63;
        u32 nd = ctrl[OFF_DUPCNT];
        if (nd > DUP_CAP) nd = DUP_CAP;
        for (u32 d = (u32)wv; d < nd; d += (u32)NW) {
            u64 e = dupList[d];
            u32 key = (u32)(e >> 32);
            u32 lr = (u32)e;
            u32 b = key >> 16;
            u32 r = hoff[b] + lr;
            u32 s0 = bstart[b];
            u32 m = bstart[b + 1] - s0;
            if (lane < 32) {
                f4 acc = {0.f, 0.f, 0.f, 0.f};
                u32 prevP = 0;
                bool firstIter = true;
                for (;;) {  // next-smallest original index among equal keys
                    u32 best = 0xFFFFFFFFu;
                    for (u32 k = 0; k < m; ++k) {
                        u64 vk = bucketed[s0 + k];
                        if ((u32)(vk >> 32) == key) {
                            u32 pk = (u32)vk;
                            if ((firstIter || pk > prevP) && pk < best) best = pk;
                        }
                    }
                    if (best == 0xFFFFFFFFu) break;
                    acc += F[(size_t)best * 32 + lane];
                    prevP = best;
                    firstIter = false;
                }
                O[(size_t)r * 32 + lane] = acc;
            }
        }
    }

    // tail zero: rows [nUnique, N)
    {
        u32 nU = hoff[NBUCKET];
        u32 tailQuads = ((u32)N - nU) * 32u;
        const u32 tot = G_BLOCKS * 256;
        f4 z = {0.f, 0.f, 0.f, 0.f};
        for (u32 t = (u32)gid; t < tailQuads; t += tot) {
            u32 row = nU + (t >> 5);
            O[(size_t)row * 32 + (t & 31)] = z;
        }
    }
}

extern "C" void kernel_launch(void* const* d_in, const int* in_sizes, int n_in,
                              void* d_out, int out_size, void* d_ws, size_t ws_size,
                              hipStream_t stream) {
    const int* coords = (const int*)d_in[0];
    const float* feats = (const float*)d_in[1];
    float* out = (float*)d_out;

    char* w = (char*)d_ws;
    u64* bucketed    = (u64*)(w);                              // 2 MiB
    u64* keyslot     = (u64*)(w + (size_t)2 * 1024 * 1024);    // 2 MiB
    u32* inv_partial = (u32*)(w + (size_t)4 * 1024 * 1024);    // 1 MiB
    u64* dupList     = (u64*)(w + (size_t)5 * 1024 * 1024);    // 512 KiB
    u32* ctrl        = (u32*)(w + (size_t)5 * 1024 * 1024 + 512 * 1024);  // ~257 KiB

    // zero hist + dupCount (contiguous 16385 words)
    hipMemsetAsync(ctrl, 0, (size_t)16385 * sizeof(u32), stream);

    kA<<<N / 256, 256, 0, stream>>>(coords, keyslot, ctrl);
    k_scan<<<1, 1024, 0, stream>>>(ctrl + OFF_HIST, ctrl + OFF_BSTART);
    kC<<<N / 256, 256, 0, stream>>>(keyslot, ctrl, bucketed);
    kD<<<NBUCKET / 4, 256, 0, stream>>>(bucketed, inv_partial, dupList, ctrl);
    k_scan<<<1, 1024, 0, stream>>>(ctrl + OFF_HCNT, ctrl + OFF_HOFF);
    kG<<<G_BLOCKS, 256, 0, stream>>>(inv_partial, feats, bucketed, dupList, ctrl, out);
}